// Round 1
// baseline (239.585 us; speedup 1.0000x reference)
//
#include <hip/hip_runtime.h>

#define TW 32
#define TH 32
#define RD 5
#define KW 11
#define HP (TH + 2*RD)   // 42 rows with halo
#define WP (TW + 2*RD)   // 42 cols with halo
#define IMG 512
#define NPLANES 48       // 16*3
#define NTILES_X (IMG / TW)          // 16
#define NTILES_Y (IMG / TH)          // 16
#define TILES_PER_PLANE (NTILES_X * NTILES_Y)  // 256
#define NBLOCKS (NPLANES * TILES_PER_PLANE)    // 12288
#define NPIX (16.0f * 3.0f * 512.0f * 512.0f)

__constant__ float c_w[KW] = {
    0.00102838f, 0.00759876f, 0.03600077f, 0.10936069f, 0.21300553f,
    0.26601172f,
    0.21300553f, 0.10936069f, 0.03600077f, 0.00759876f, 0.00102838f
};

__global__ __launch_bounds__(256) void ssim_tile_kernel(
    const float* __restrict__ img1, const float* __restrict__ img2,
    float* __restrict__ partial)
{
    __shared__ float a_s[HP][WP];
    __shared__ float b_s[HP][WP];
    __shared__ float h_mu1[HP][TW];
    __shared__ float h_mu2[HP][TW];
    __shared__ float h_x11[HP][TW];
    __shared__ float h_x22[HP][TW];
    __shared__ float h_x12[HP][TW];

    const int tid = threadIdx.x;
    const int blk = blockIdx.x;
    const int plane = blk / TILES_PER_PLANE;
    const int t     = blk % TILES_PER_PLANE;
    const int ty0 = (t / NTILES_X) * TH;
    const int tx0 = (t % NTILES_X) * TW;
    const float* __restrict__ p1 = img1 + (size_t)plane * IMG * IMG;
    const float* __restrict__ p2 = img2 + (size_t)plane * IMG * IMG;

    // ---- stage inputs with halo (zero padding = SAME conv padding) ----
    for (int idx = tid; idx < HP * WP; idx += 256) {
        const int r = idx / WP, c = idx % WP;
        const int gy = ty0 + r - RD, gx = tx0 + c - RD;
        float av = 0.f, bv = 0.f;
        if (gy >= 0 && gy < IMG && gx >= 0 && gx < IMG) {
            const int g = gy * IMG + gx;
            av = p1[g];
            bv = p2[g];
        }
        a_s[r][c] = av;
        b_s[r][c] = bv;
    }
    __syncthreads();

    // ---- horizontal separable pass: 5 windowed sums ----
    for (int idx = tid; idx < HP * TW; idx += 256) {
        const int r = idx >> 5, c = idx & 31;   // TW == 32
        float sa = 0.f, sb = 0.f, saa = 0.f, sbb = 0.f, sab = 0.f;
        #pragma unroll
        for (int dx = 0; dx < KW; dx++) {
            const float wv = c_w[dx];
            const float av = a_s[r][c + dx];
            const float bv = b_s[r][c + dx];
            const float wa = wv * av;
            const float wb = wv * bv;
            sa  += wa;
            sb  += wb;
            saa += wa * av;
            sbb += wb * bv;
            sab += wa * bv;
        }
        h_mu1[r][c] = sa;
        h_mu2[r][c] = sb;
        h_x11[r][c] = saa;
        h_x22[r][c] = sbb;
        h_x12[r][c] = sab;
    }
    __syncthreads();

    // ---- vertical pass + SSIM map + per-thread accumulation ----
    const float C1 = 1e-4f;   // 0.01^2
    const float C2 = 9e-4f;   // 0.03^2
    float acc = 0.f;
    for (int idx = tid; idx < TH * TW; idx += 256) {
        const int r = idx >> 5, c = idx & 31;
        float mu1 = 0.f, mu2 = 0.f, x11 = 0.f, x22 = 0.f, x12 = 0.f;
        #pragma unroll
        for (int dy = 0; dy < KW; dy++) {
            const float wv = c_w[dy];
            mu1 += wv * h_mu1[r + dy][c];
            mu2 += wv * h_mu2[r + dy][c];
            x11 += wv * h_x11[r + dy][c];
            x22 += wv * h_x22[r + dy][c];
            x12 += wv * h_x12[r + dy][c];
        }
        const float mu1s = mu1 * mu1;
        const float mu2s = mu2 * mu2;
        const float mu12 = mu1 * mu2;
        const float s1  = x11 - mu1s;
        const float s2  = x22 - mu2s;
        const float s12 = x12 - mu12;
        const float num = (2.f * mu12 + C1) * (2.f * s12 + C2);
        const float den = (mu1s + mu2s + C1) * (s1 + s2 + C2);
        acc += num / den;
    }

    // ---- block reduction (wave64 shuffle, then 4 waves via LDS) ----
    #pragma unroll
    for (int off = 32; off > 0; off >>= 1)
        acc += __shfl_down(acc, off, 64);

    __shared__ float wsum[4];
    const int lane = tid & 63;
    const int wv_i = tid >> 6;
    if (lane == 0) wsum[wv_i] = acc;
    __syncthreads();
    if (tid == 0)
        partial[blk] = (wsum[0] + wsum[1]) + (wsum[2] + wsum[3]);
}

__global__ __launch_bounds__(256) void ssim_reduce_kernel(
    const float* __restrict__ partial, float* __restrict__ out)
{
    float acc = 0.f;
    for (int i = threadIdx.x; i < NBLOCKS; i += 256)
        acc += partial[i];
    #pragma unroll
    for (int off = 32; off > 0; off >>= 1)
        acc += __shfl_down(acc, off, 64);
    __shared__ float wsum[4];
    const int lane = threadIdx.x & 63;
    const int wv_i = threadIdx.x >> 6;
    if (lane == 0) wsum[wv_i] = acc;
    __syncthreads();
    if (threadIdx.x == 0)
        out[0] = ((wsum[0] + wsum[1]) + (wsum[2] + wsum[3])) * (1.0f / NPIX);
}

extern "C" void kernel_launch(void* const* d_in, const int* in_sizes, int n_in,
                              void* d_out, int out_size, void* d_ws, size_t ws_size,
                              hipStream_t stream) {
    const float* img1 = (const float*)d_in[0];
    const float* img2 = (const float*)d_in[1];
    float* out = (float*)d_out;
    float* partial = (float*)d_ws;   // NBLOCKS floats of scratch

    ssim_tile_kernel<<<NBLOCKS, 256, 0, stream>>>(img1, img2, partial);
    ssim_reduce_kernel<<<1, 256, 0, stream>>>(partial, out);
}

// Round 2
// 164.488 us; speedup vs baseline: 1.4566x; 1.4566x over previous
//
#include <hip/hip_runtime.h>

#define IMG 512
#define NPLANES 48            // 16*3
#define TW 64                 // output tile width
#define TH 32                 // output tile height
#define RD 5
#define KW 11
#define VC (TW + 2*RD)        // 74 columns of vertical sums
#define WPAD 80               // padded LDS row (16B-aligned float4 rows)
#define NTX (IMG/TW)          // 8
#define NTY (IMG/TH)          // 16
#define TPP (NTX*NTY)         // 128
#define NBLOCKS (NPLANES*TPP) // 6144
#define NPIX (16.0f*3.0f*512.0f*512.0f)

__device__ __forceinline__ float fast_rcp(float d) {
    float r = __builtin_amdgcn_rcpf(d);
    r = r * (2.0f - d * r);   // one Newton step: ~1e-7 rel error
    return r;
}

__global__ __launch_bounds__(256) void ssim_kernel(
    const float* __restrict__ img1, const float* __restrict__ img2,
    float* __restrict__ partial)
{
    // vertical windowed sums: mu1, mu2, E[aa], E[bb], E[ab]
    __shared__ float v[5][TH][WPAD];
    __shared__ float wsum[4];

    const float cw[KW] = {
        0.00102838f, 0.00759876f, 0.03600077f, 0.10936069f, 0.21300553f,
        0.26601172f,
        0.21300553f, 0.10936069f, 0.03600077f, 0.00759876f, 0.00102838f
    };

    const int tid = threadIdx.x;
    const int blk = blockIdx.x;
    const int plane = blk / TPP;
    const int t     = blk % TPP;
    const int ty0 = (t / NTX) * TH;
    const int tx0 = (t % NTX) * TW;
    const float* __restrict__ p1 = img1 + (size_t)plane * IMG * IMG;
    const float* __restrict__ p2 = img2 + (size_t)plane * IMG * IMG;

    // ---- pass 1: vertical 11-tap on raw + product images, global -> LDS ----
    // 296 tasks: (col 0..73) x (4 row-segments of 8 outputs)
    for (int task = tid; task < VC * 4; task += 256) {
        const int col = task % VC;       // storage column
        const int seg = task / VC;       // 0..3
        const int gx  = tx0 + col - RD;
        const bool xok = (gx >= 0) && (gx < IMG);
        const int r0 = seg * 8;

        float a[18], b[18];
        #pragma unroll
        for (int k = 0; k < 18; k++) {
            const int gy = ty0 + r0 + k - RD;
            const bool ok = xok && (gy >= 0) && (gy < IMG);
            const int gi = gy * IMG + gx;
            a[k] = ok ? p1[gi] : 0.f;
            b[k] = ok ? p2[gi] : 0.f;
        }

        #pragma unroll
        for (int k = 0; k < 8; k++) {
            float sa = 0.f, sb = 0.f, saa = 0.f, sbb = 0.f, sab = 0.f;
            #pragma unroll
            for (int d = 0; d < KW; d++) {
                const float wv = cw[d];
                const float av = a[k + d];
                const float bv = b[k + d];
                const float wa = wv * av;
                const float wb = wv * bv;
                sa  += wa;
                sb  += wb;
                saa += wa * av;
                sbb += wb * bv;
                sab += wa * bv;
            }
            const int r = r0 + k;
            v[0][r][col] = sa;
            v[1][r][col] = sb;
            v[2][r][col] = saa;
            v[3][r][col] = sbb;
            v[4][r][col] = sab;
        }
    }
    __syncthreads();

    // ---- pass 2: horizontal 11-tap (vectorized ds_read_b128) + SSIM ----
    const float C1 = 1e-4f;
    const float C2 = 9e-4f;
    float acc = 0.f;
    #pragma unroll
    for (int it = 0; it < 2; it++) {
        const int task = tid + it * 256;     // 0..511
        const int j = task & 15;             // float4 group: outputs 4j..4j+3
        const int r = task >> 4;             // row 0..31
        float res[5][4];
        #pragma unroll
        for (int arr = 0; arr < 5; arr++) {
            const float4* row = (const float4*)&v[arr][r][0];
            const float4 q0 = row[j + 0];
            const float4 q1 = row[j + 1];
            const float4 q2 = row[j + 2];
            const float4 q3 = row[j + 3];
            const float vals[16] = {
                q0.x, q0.y, q0.z, q0.w,
                q1.x, q1.y, q1.z, q1.w,
                q2.x, q2.y, q2.z, q2.w,
                q3.x, q3.y, q3.z, q3.w
            };
            #pragma unroll
            for (int o = 0; o < 4; o++) {
                float s = 0.f;
                #pragma unroll
                for (int d = 0; d < KW; d++)
                    s += cw[d] * vals[o + d];
                res[arr][o] = s;
            }
        }
        #pragma unroll
        for (int o = 0; o < 4; o++) {
            const float mu1 = res[0][o];
            const float mu2 = res[1][o];
            const float x11 = res[2][o];
            const float x22 = res[3][o];
            const float x12 = res[4][o];
            const float mu1s = mu1 * mu1;
            const float mu2s = mu2 * mu2;
            const float mu12 = mu1 * mu2;
            const float s1  = x11 - mu1s;
            const float s2  = x22 - mu2s;
            const float s12 = x12 - mu12;
            const float num = (2.f * mu12 + C1) * (2.f * s12 + C2);
            const float den = (mu1s + mu2s + C1) * (s1 + s2 + C2);
            acc += num * fast_rcp(den);
        }
    }

    // ---- block reduction ----
    #pragma unroll
    for (int off = 32; off > 0; off >>= 1)
        acc += __shfl_down(acc, off, 64);
    const int lane = tid & 63;
    const int wv_i = tid >> 6;
    if (lane == 0) wsum[wv_i] = acc;
    __syncthreads();
    if (tid == 0)
        partial[blk] = (wsum[0] + wsum[1]) + (wsum[2] + wsum[3]);
}

__global__ __launch_bounds__(256) void ssim_reduce_kernel(
    const float* __restrict__ partial, float* __restrict__ out)
{
    float acc = 0.f;
    for (int i = threadIdx.x; i < NBLOCKS; i += 256)
        acc += partial[i];
    #pragma unroll
    for (int off = 32; off > 0; off >>= 1)
        acc += __shfl_down(acc, off, 64);
    __shared__ float wsum[4];
    const int lane = threadIdx.x & 63;
    const int wv_i = threadIdx.x >> 6;
    if (lane == 0) wsum[wv_i] = acc;
    __syncthreads();
    if (threadIdx.x == 0)
        out[0] = ((wsum[0] + wsum[1]) + (wsum[2] + wsum[3])) * (1.0f / NPIX);
}

extern "C" void kernel_launch(void* const* d_in, const int* in_sizes, int n_in,
                              void* d_out, int out_size, void* d_ws, size_t ws_size,
                              hipStream_t stream) {
    const float* img1 = (const float*)d_in[0];
    const float* img2 = (const float*)d_in[1];
    float* out = (float*)d_out;
    float* partial = (float*)d_ws;   // NBLOCKS floats of scratch

    ssim_kernel<<<NBLOCKS, 256, 0, stream>>>(img1, img2, partial);
    ssim_reduce_kernel<<<1, 256, 0, stream>>>(partial, out);
}